// Round 10
// baseline (148.368 us; speedup 1.0000x reference)
//
#include <hip/hip_runtime.h>
#include <hip/hip_bf16.h>

#define C 1000
#define D 128
#define PAD 16            // one atomic target per 64B line

__device__ __forceinline__ void atomAddF(float* p, float v) { unsafeAtomicAdd(p, v); }

// Phase 1: histogram of target classes (LDS u32 atomics -> native ds_add).
__global__ __launch_bounds__(1024)
void k_hist(const int* __restrict__ tgt, unsigned* __restrict__ counts, int N) {
    __shared__ unsigned lh[C];
    const int t = threadIdx.x;
    if (t < C) lh[t] = 0u;
    __syncthreads();
    for (int i = blockIdx.x * 1024 + t; i < N; i += gridDim.x * 1024)
        atomicAdd(&lh[tgt[i]], 1u);
    __syncthreads();
    if (t < C) atomicAdd(&counts[t * PAD], lh[t]);
}

// Phase 2: exclusive scan over 1000 counts -> offsets + scatter cursors.
__global__ __launch_bounds__(1024)
void k_scan(const unsigned* __restrict__ counts, int* __restrict__ off,
            int* __restrict__ cursor) {
    __shared__ unsigned a[1024];
    const int t = threadIdx.x;
    const unsigned mine = (t < C) ? counts[t * PAD] : 0u;
    a[t] = mine;
    for (int o = 1; o < 1024; o <<= 1) {
        __syncthreads();
        const unsigned v = (t >= o) ? a[t - o] : 0u;
        __syncthreads();
        a[t] += v;
    }
    __syncthreads();
    if (t < C) {
        const unsigned excl = a[t] - mine;
        off[t] = (int)excl;
        cursor[t * PAD] = (int)excl;
    }
}

// Phase 3: scatter row indices into class-grouped order[].
__global__ __launch_bounds__(256)
void k_scatter(const int* __restrict__ tgt, int* __restrict__ cursor,
               int* __restrict__ order, int N) {
    const int i = blockIdx.x * 256 + threadIdx.x;
    if (i >= N) return;
    const int c = tgt[i];
    const int pos = atomicAdd(&cursor[c * PAD], 1);
    order[pos] = i;
}

// Phase 4: per-class sums -> means (global, L2-resident for phase 5).
// One block per class, 8 waves, half-wave = one 512B row, 4 rows in flight.
// Measured standalone (round 7): ~53 us = 4.8 TB/s gather.
__global__ __launch_bounds__(512)
void k_sums(const float* __restrict__ emb, const int* __restrict__ order,
            const int* __restrict__ off, const unsigned* __restrict__ counts,
            float* __restrict__ means) {
    __shared__ float part[8][D];
    const int c    = blockIdx.x;
    const int t    = threadIdx.x;
    const int w    = t >> 6;
    const int lane = t & 63;
    const int half = lane >> 5;
    const int sub  = lane & 31;
    const int start = off[c];
    const int cnt   = (int)counts[c * PAD];

    const int chunk = (cnt + 7) >> 3;
    const int wsrt  = start + w * chunk;
    const int wend  = min(start + cnt, wsrt + chunk);
    float ax = 0.f, ay = 0.f, az = 0.f, aw = 0.f;
    int pos = wsrt + half;
    for (; pos + 6 < wend; pos += 8) {              // 4 rows in flight / half-wave
        const int r0 = order[pos];
        const int r1 = order[pos + 2];
        const int r2 = order[pos + 4];
        const int r3 = order[pos + 6];
        const float4 v0 = *reinterpret_cast<const float4*>(emb + (size_t)r0 * D + sub * 4);
        const float4 v1 = *reinterpret_cast<const float4*>(emb + (size_t)r1 * D + sub * 4);
        const float4 v2 = *reinterpret_cast<const float4*>(emb + (size_t)r2 * D + sub * 4);
        const float4 v3 = *reinterpret_cast<const float4*>(emb + (size_t)r3 * D + sub * 4);
        ax += v0.x + v1.x + v2.x + v3.x;
        ay += v0.y + v1.y + v2.y + v3.y;
        az += v0.z + v1.z + v2.z + v3.z;
        aw += v0.w + v1.w + v2.w + v3.w;
    }
    for (; pos < wend; pos += 2) {
        const int r0 = order[pos];
        const float4 v0 = *reinterpret_cast<const float4*>(emb + (size_t)r0 * D + sub * 4);
        ax += v0.x; ay += v0.y; az += v0.z; aw += v0.w;
    }
    ax += __shfl_xor(ax, 32);
    ay += __shfl_xor(ay, 32);
    az += __shfl_xor(az, 32);
    aw += __shfl_xor(aw, 32);
    if (half == 0) {
        part[w][sub * 4 + 0] = ax;
        part[w][sub * 4 + 1] = ay;
        part[w][sub * 4 + 2] = az;
        part[w][sub * 4 + 3] = aw;
    }
    __syncthreads();
    if (t < D) {
        float s = 0.f;
        #pragma unroll
        for (int k = 0; k < 8; ++k) s += part[k][t];
        means[c * D + t] = s / fmaxf((float)cnt, 1.f);
    }
}

// Phase 5: linear-coalesced norms. Half-wave per row in NATURAL row order
// (consecutive half-waves -> consecutive 512B rows: fully coalesced, no
// indirection). emb re-read is LLC-hot (proved round 8); means is L2-hot.
// 2 rows in flight per half-wave, interleaved shfl chains; 1 atomic/row.
__global__ __launch_bounds__(256)
void k_norms_coal(const float* __restrict__ emb, const int* __restrict__ tgt,
                  const float* __restrict__ means, float* __restrict__ normsums,
                  int N) {
    const int gid  = blockIdx.x * 256 + threadIdx.x;
    const int lane = gid & 63;
    const int half = lane >> 5;
    const int sub  = lane & 31;
    const int wid  = gid >> 6;
    const int nw   = (gridDim.x * 256) >> 6;

    for (int base = wid * 4; base < N; base += nw * 4) {
        const int r0 = base + half * 2;       // this half-wave's two rows
        const int r1 = r0 + 1;
        if (r1 < N) {
            const int c0 = tgt[r0];
            const int c1 = tgt[r1];
            const float4 v0 = *reinterpret_cast<const float4*>(emb + (size_t)r0 * D + sub * 4);
            const float4 v1 = *reinterpret_cast<const float4*>(emb + (size_t)r1 * D + sub * 4);
            const float4 m0 = *reinterpret_cast<const float4*>(means + (size_t)c0 * D + sub * 4);
            const float4 m1 = *reinterpret_cast<const float4*>(means + (size_t)c1 * D + sub * 4);
            float dx, dy, dz, dw;
            dx = v0.x - m0.x; dy = v0.y - m0.y; dz = v0.z - m0.z; dw = v0.w - m0.w;
            float p0 = dx * dx + dy * dy + dz * dz + dw * dw;
            dx = v1.x - m1.x; dy = v1.y - m1.y; dz = v1.z - m1.z; dw = v1.w - m1.w;
            float p1 = dx * dx + dy * dy + dz * dz + dw * dw;
            p0 += __shfl_xor(p0, 1);  p1 += __shfl_xor(p1, 1);
            p0 += __shfl_xor(p0, 2);  p1 += __shfl_xor(p1, 2);
            p0 += __shfl_xor(p0, 4);  p1 += __shfl_xor(p1, 4);
            p0 += __shfl_xor(p0, 8);  p1 += __shfl_xor(p1, 8);
            p0 += __shfl_xor(p0, 16); p1 += __shfl_xor(p1, 16);
            if (sub == 0) {
                atomAddF(&normsums[c0 * PAD], sqrtf(p0));
                atomAddF(&normsums[c1 * PAD], sqrtf(p1));
            }
        } else if (r0 < N) {
            const int c0 = tgt[r0];
            const float4 v0 = *reinterpret_cast<const float4*>(emb + (size_t)r0 * D + sub * 4);
            const float4 m0 = *reinterpret_cast<const float4*>(means + (size_t)c0 * D + sub * 4);
            const float dx = v0.x - m0.x, dy = v0.y - m0.y, dz = v0.z - m0.z, dw = v0.w - m0.w;
            float p0 = dx * dx + dy * dy + dz * dz + dw * dw;
            p0 += __shfl_xor(p0, 1);
            p0 += __shfl_xor(p0, 2);
            p0 += __shfl_xor(p0, 4);
            p0 += __shfl_xor(p0, 8);
            p0 += __shfl_xor(p0, 16);
            if (sub == 0) atomAddF(&normsums[c0 * PAD], sqrtf(p0));
        }
    }
}

// Phase 6: final scalar = sum_c (count>0 ? normsum/count : 0).
__global__ __launch_bounds__(256)
void k_final(const unsigned* __restrict__ counts, const float* __restrict__ normsums,
             float* __restrict__ out) {
    __shared__ float red[256];
    float acc = 0.f;
    for (int c = threadIdx.x; c < C; c += 256) {
        const unsigned cnt = counts[c * PAD];
        if (cnt > 0u) acc += normsums[c * PAD] / (float)cnt;
    }
    red[threadIdx.x] = acc;
    __syncthreads();
    for (int s = 128; s > 0; s >>= 1) {
        if (threadIdx.x < s) red[threadIdx.x] += red[threadIdx.x + s];
        __syncthreads();
    }
    if (threadIdx.x == 0) out[0] = red[0];
}

extern "C" void kernel_launch(void* const* d_in, const int* in_sizes, int n_in,
                              void* d_out, int out_size, void* d_ws, size_t ws_size,
                              hipStream_t stream) {
    const float* emb = (const float*)d_in[0];
    const int*   tgt = (const int*)d_in[1];
    const int N = in_sizes[1];

    char* ws = (char*)d_ws;
    unsigned* counts   = (unsigned*)(ws);            // C*PAD u32 (zeroed)
    float*    normsums = (float*)(ws + 65536);       // C*PAD f32 (zeroed)
    int*      off      = (int*)(ws + 131072);        // C ints
    int*      cursor   = (int*)(ws + 139264);        // C*PAD ints
    float*    means    = (float*)(ws + 204800);      // C*D f32 = 512000 B
    int*      order    = (int*)(ws + 720896);        // N ints = 2 MB

    hipMemsetAsync(d_ws, 0, 131072, stream);         // counts + normsums

    k_hist<<<256, 1024, 0, stream>>>(tgt, counts, N);
    k_scan<<<1, 1024, 0, stream>>>(counts, off, cursor);
    k_scatter<<<(N + 255) / 256, 256, 0, stream>>>(tgt, cursor, order, N);
    k_sums<<<C, 512, 0, stream>>>(emb, order, off, counts, means);
    k_norms_coal<<<2048, 256, 0, stream>>>(emb, tgt, means, normsums, N);
    k_final<<<1, 256, 0, stream>>>(counts, normsums, (float*)d_out);
}